// Round 1
// baseline (82.781 us; speedup 1.0000x reference)
//
#include <hip/hip_runtime.h>
#include <math.h>

// Problem constants (match reference)
#define B_ROWS 4096
#define D_DIM  512
#define N_ROWS 8192
#define R_NEG  4

// 1/(TEMPERATURE + EPSILON): fp32(1/(0.5+1e-8)) == 2.0f (verified absmax 0.0 in R1)
#define INV_T 2.0f

#define NORM_BLOCKS (N_ROWS / 4)  // kernel A: 4 waves/block, 1 row/wave
#define LOSS_BLOCKS (N_ROWS / 2)  // kernel B: 4 waves/block, 2 waves/row
#define RED_ITERS   (LOSS_BLOCKS / 256)

// R5 journal:
//  - top-5 dispatches are all 268MB fillBufferAligned @ ~6.4 TB/s (= workspace
//    re-poison at HBM-write roofline, ~42us fixed floor). Fused kernel ~32us.
//  - fused kernel is latency-bound (~3 TB/s effective on 96MB logical reads):
//    40 gather-dest VGPRs -> ~100+ VGPR -> 4 waves/SIMD; caches cold after the
//    268MB poison flush; 11 redundant shuffle-reductions (bb recomputed ~6x).
//  - fix: (A) linear invnorm pass (removes all bb work, re-warms L3),
//         (B) 2 waves/row gather kernel: 6 loads + 5 reductions per wave,
//             __launch_bounds__(256,8) targeting <=64 VGPR / 8 waves per SIMD.

__device__ __forceinline__ float dot4(float4 a, float4 b) {
  return a.x * b.x + a.y * b.y + a.z * b.z + a.w * b.w;
}

// ---------------------------------------------------------------------------
// Kernel A: inverse norms, one wave per row. Linear full-BW sweep of z (16MB)
// -> also refills L3 with z right after the workspace-poison flush, so kernel
// B's random gathers hit L3 instead of HBM.
// ---------------------------------------------------------------------------
__global__ __launch_bounds__(256, 8) void norm_kernel(
    const float* __restrict__ zi, const float* __restrict__ zj,
    float* __restrict__ invn) {
  const int wave = threadIdx.x >> 6;
  const int lane = threadIdx.x & 63;
  const int row  = blockIdx.x * 4 + wave;

  const float4* a4 =
      (row < B_ROWS) ? (const float4*)(zi + (size_t)row * D_DIM)
                     : (const float4*)(zj + (size_t)(row - B_ROWS) * D_DIM);
  float4 a0 = a4[lane];
  float4 a1 = a4[lane + 64];
  float aa = dot4(a0, a0) + dot4(a1, a1);
#pragma unroll
  for (int off = 32; off > 0; off >>= 1) aa += __shfl_down(aa, off);
  if (lane == 0) invn[row] = 1.0f / fmaxf(sqrtf(aa), 1e-8f);
}

// ---------------------------------------------------------------------------
// Kernel B: gathered dots + log-softmax. TWO waves per row (half row each):
// 6 float4 loads/wave, 5 accumulators, 5 shuffle-reductions -> low VGPR,
// 8 waves/SIMD, 2x the resident waves to hide gather latency.
// Ends with one plain store per block (no atomics — R3: 2048 same-address
// atomicAdds serialize ~30cyc each at the TCC; no fence — R2: +81us).
// ---------------------------------------------------------------------------
__global__ __launch_bounds__(256, 8) void loss_kernel(
    const float* __restrict__ zi, const float* __restrict__ zj,
    const int* __restrict__ neg_idx, const float* __restrict__ invn,
    float* __restrict__ partials) {
  __shared__ float s_ab[4][5];
  __shared__ float s_nll[2];

  const int wave = threadIdx.x >> 6;
  const int lane = threadIdx.x & 63;
  const int rloc = wave >> 1;   // 0/1: which of the block's two rows
  const int half = wave & 1;    // 0/1: which half of the row
  const int row  = blockIdx.x * 2 + rloc;

  // Gathered column indices (wave-uniform)
  const int4 nv = ((const int4*)neg_idx)[row];
  int cols[5];
  cols[0] = (row + B_ROWS) & (N_ROWS - 1);       // positive column
  cols[1] = nv.x + (nv.x >= row ? 1 : 0);        // skip-diagonal mapping
  cols[2] = nv.y + (nv.y >= row ? 1 : 0);
  cols[3] = nv.z + (nv.z >= row ? 1 : 0);
  cols[4] = nv.w + (nv.w >= row ? 1 : 0);

  // Wave-uniform invnorm loads (tiny, hot in cache; issue early)
  const float inv_r = invn[row];
  float invc[5];
#pragma unroll
  for (int c = 0; c < 5; ++c) invc[c] = invn[cols[c]];

  const int off = lane + half * 64;  // float4 index within the row

  const float4* a4 =
      (row < B_ROWS) ? (const float4*)(zi + (size_t)row * D_DIM)
                     : (const float4*)(zj + (size_t)(row - B_ROWS) * D_DIM);
  float4 a = a4[off];

  // Issue all 5 gather loads before any use (memory-level parallelism)
  float4 b[5];
#pragma unroll
  for (int c = 0; c < 5; ++c) {
    const int col = cols[c];
    const float4* b4 =
        (col < B_ROWS) ? (const float4*)(zi + (size_t)col * D_DIM)
                       : (const float4*)(zj + (size_t)(col - B_ROWS) * D_DIM);
    b[c] = b4[off];
  }

  float ab[5];
#pragma unroll
  for (int c = 0; c < 5; ++c) ab[c] = dot4(a, b[c]);

  // 5 simultaneous wave reductions
#pragma unroll
  for (int o = 32; o > 0; o >>= 1) {
#pragma unroll
    for (int c = 0; c < 5; ++c) ab[c] += __shfl_down(ab[c], o);
  }

  if (lane == 0) {
#pragma unroll
    for (int c = 0; c < 5; ++c) s_ab[wave][c] = ab[c];
  }
  __syncthreads();

  // One finalizer lane per row (waves 0 and 2 hold the right uniforms)
  if (lane == 0 && half == 0) {
    float logits[5];
    float m = -INFINITY;
#pragma unroll
    for (int c = 0; c < 5; ++c) {
      const float abf = s_ab[wave][c] + s_ab[wave + 1][c];
      logits[c] = abf * inv_r * invc[c] * INV_T;
      m = fmaxf(m, logits[c]);
    }
    float sum = 0.0f;
#pragma unroll
    for (int c = 0; c < 5; ++c) sum += __expf(logits[c] - m);
    s_nll[rloc] = -(logits[0] - m - __logf(sum));
  }
  __syncthreads();

  if (threadIdx.x == 0) {
    partials[blockIdx.x] = s_nll[0] + s_nll[1];
  }
}

// ---------------------------------------------------------------------------
// Kernel C: reduce LOSS_BLOCKS partials -> mean -> out[0]. One block.
// ---------------------------------------------------------------------------
__global__ __launch_bounds__(256) void reduce_kernel(
    const float* __restrict__ partials, float* __restrict__ out) {
  __shared__ float smem[4];
  const int lane = threadIdx.x & 63;
  const int wave = threadIdx.x >> 6;
  float s = 0.0f;
#pragma unroll
  for (int i = 0; i < RED_ITERS; ++i) s += partials[i * 256 + threadIdx.x];
#pragma unroll
  for (int off = 32; off > 0; off >>= 1) s += __shfl_down(s, off);
  if (lane == 0) smem[wave] = s;
  __syncthreads();
  if (threadIdx.x == 0) {
    out[0] = (smem[0] + smem[1] + smem[2] + smem[3]) * (1.0f / (float)N_ROWS);
  }
}

extern "C" void kernel_launch(void* const* d_in, const int* in_sizes, int n_in,
                              void* d_out, int out_size, void* d_ws,
                              size_t ws_size, hipStream_t stream) {
  const float* zi      = (const float*)d_in[0];
  const float* zj      = (const float*)d_in[1];
  const int*   neg_idx = (const int*)d_in[2];
  float* out = (float*)d_out;

  float* invn     = (float*)d_ws;          // N_ROWS floats, fully written
  float* partials = invn + N_ROWS;         // LOSS_BLOCKS floats, fully written

  norm_kernel<<<dim3(NORM_BLOCKS), dim3(256), 0, stream>>>(zi, zj, invn);
  loss_kernel<<<dim3(LOSS_BLOCKS), dim3(256), 0, stream>>>(zi, zj, neg_idx,
                                                           invn, partials);
  reduce_kernel<<<dim3(1), dim3(256), 0, stream>>>(partials, out);
}

// Round 2
// 77.262 us; speedup vs baseline: 1.0714x; 1.0714x over previous
//
#include <hip/hip_runtime.h>
#include <hip/hip_fp16.h>
#include <math.h>

// Problem constants (match reference)
#define B_ROWS 4096
#define D_DIM  512
#define N_ROWS 8192
#define R_NEG  4

// 1/(TEMPERATURE + EPSILON): fp32(1/(0.5+1e-8)) == 2.0f (verified absmax 0.0 in R1)
#define INV_T 2.0f

#define NORM_BLOCKS (N_ROWS / 4)  // kernel A: 4 waves/block, 1 row/wave
#define LOSS_BLOCKS (N_ROWS / 4)  // kernel B: 4 waves/block, 1 row/wave
#define RED_ITERS   (LOSS_BLOCKS / 256)

// Journal:
//  R0-R4 (prev session): fill = 268MB workspace poison @6.4TB/s = ~41us fixed
//    floor, in the timed window every iteration. No atomics (R3), no fence (R2).
//  R5: split norm pass + 2 waves/row (2x occupancy, low VGPR) -> NULL on the
//    loss kernel, total +4us (= norm+launch cost). Falsifies latency-bound
//    theory: loss kernel is MEMORY-THROUGHPUT bound. The poison's 268MB of
//    dirty L3 lines drain to HBM *during* our kernels and evict z each iter,
//    so the ~96MB logical gather stream runs at ~3TB/s effective.
//  R6 (this): byte reduction — norm pass writes NORMALIZED fp16 z (8MB) to
//    workspace; gather kernel reads fp16 only (48MB logical, no invn loads,
//    dots are logits directly). Predict loss kernel ~halves; total ~64-70us.

__device__ __forceinline__ float dot4(float4 a, float4 b) {
  return a.x * b.x + a.y * b.y + a.z * b.z + a.w * b.w;
}

// 8-element fp16 dot with fp32 accumulate (inputs are 4x half2 packed in uint4)
__device__ __forceinline__ float dot8h(uint4 a, uint4 b) {
  const __half2* ah = (const __half2*)&a;
  const __half2* bh = (const __half2*)&b;
  float s = 0.0f;
#pragma unroll
  for (int k = 0; k < 4; ++k) {
    float2 af = __half22float2(ah[k]);
    float2 bf = __half22float2(bh[k]);
    s += af.x * bf.x + af.y * bf.y;
  }
  return s;
}

// ---------------------------------------------------------------------------
// Kernel A: one wave per row. Reads fp32 z (16MB linear), computes invnorm,
// writes NORMALIZED fp16 row (8MB) to workspace. Butterfly reduce so every
// lane holds the norm.
// ---------------------------------------------------------------------------
__global__ __launch_bounds__(256, 8) void norm_kernel(
    const float* __restrict__ zi, const float* __restrict__ zj,
    __half* __restrict__ zh) {
  const int wave = threadIdx.x >> 6;
  const int lane = threadIdx.x & 63;
  const int row  = blockIdx.x * 4 + wave;

  const float4* a4 =
      (row < B_ROWS) ? (const float4*)(zi + (size_t)row * D_DIM)
                     : (const float4*)(zj + (size_t)(row - B_ROWS) * D_DIM);
  float4 a0 = a4[lane];
  float4 a1 = a4[lane + 64];
  float aa = dot4(a0, a0) + dot4(a1, a1);
#pragma unroll
  for (int off = 32; off > 0; off >>= 1) aa += __shfl_xor(aa, off);
  const float inv = 1.0f / fmaxf(sqrtf(aa), 1e-8f);

  // lane holds floats [4L..4L+3] and [256+4L..256+4L+3]; store as 2x 8B
  uint2* out = (uint2*)(zh + (size_t)row * D_DIM);
  union { uint2 u; __half2 h[2]; } p0, p1;
  p0.h[0] = __floats2half2_rn(a0.x * inv, a0.y * inv);
  p0.h[1] = __floats2half2_rn(a0.z * inv, a0.w * inv);
  p1.h[0] = __floats2half2_rn(a1.x * inv, a1.y * inv);
  p1.h[1] = __floats2half2_rn(a1.z * inv, a1.w * inv);
  out[lane]      = p0.u;
  out[lane + 64] = p1.u;
}

// ---------------------------------------------------------------------------
// Kernel B: gathered fp16 dots + log-softmax. One wave per row: 6 uint4
// (16B, 8 halves) loads per lane, 5 fp32 accumulators, 5 wave reductions.
// Dots of normalized rows ARE the cosine sims; logits = dot * INV_T.
// One plain store per block (no atomics/fence — see journal).
// ---------------------------------------------------------------------------
__global__ __launch_bounds__(256, 8) void loss_kernel(
    const __half* __restrict__ zh, const int* __restrict__ neg_idx,
    float* __restrict__ partials) {
  __shared__ float s_nll[4];

  const int wave = threadIdx.x >> 6;
  const int lane = threadIdx.x & 63;
  const int row  = blockIdx.x * 4 + wave;

  // Gathered column indices (wave-uniform values, per-lane computed)
  const int4 nv = ((const int4*)neg_idx)[row];
  int cols[5];
  cols[0] = (row + B_ROWS) & (N_ROWS - 1);       // positive column
  cols[1] = nv.x + (nv.x >= row ? 1 : 0);        // skip-diagonal mapping
  cols[2] = nv.y + (nv.y >= row ? 1 : 0);
  cols[3] = nv.z + (nv.z >= row ? 1 : 0);
  cols[4] = nv.w + (nv.w >= row ? 1 : 0);

  const uint4* a4 = (const uint4*)(zh + (size_t)row * D_DIM);
  uint4 a = a4[lane];

  // Issue all 5 gather loads before any use (memory-level parallelism)
  uint4 b[5];
#pragma unroll
  for (int c = 0; c < 5; ++c) {
    b[c] = ((const uint4*)(zh + (size_t)cols[c] * D_DIM))[lane];
  }

  float ab[5];
#pragma unroll
  for (int c = 0; c < 5; ++c) ab[c] = dot8h(a, b[c]);

  // 5 simultaneous wave reductions
#pragma unroll
  for (int o = 32; o > 0; o >>= 1) {
#pragma unroll
    for (int c = 0; c < 5; ++c) ab[c] += __shfl_down(ab[c], o);
  }

  if (lane == 0) {
    float logits[5];
    float m = -INFINITY;
#pragma unroll
    for (int c = 0; c < 5; ++c) {
      logits[c] = ab[c] * INV_T;
      m = fmaxf(m, logits[c]);
    }
    float sum = 0.0f;
#pragma unroll
    for (int c = 0; c < 5; ++c) sum += __expf(logits[c] - m);
    s_nll[wave] = -(logits[0] - m - __logf(sum));
  }
  __syncthreads();

  if (threadIdx.x == 0) {
    partials[blockIdx.x] = s_nll[0] + s_nll[1] + s_nll[2] + s_nll[3];
  }
}

// ---------------------------------------------------------------------------
// Kernel C: reduce LOSS_BLOCKS partials -> mean -> out[0]. One block.
// ---------------------------------------------------------------------------
__global__ __launch_bounds__(256) void reduce_kernel(
    const float* __restrict__ partials, float* __restrict__ out) {
  __shared__ float smem[4];
  const int lane = threadIdx.x & 63;
  const int wave = threadIdx.x >> 6;
  float s = 0.0f;
#pragma unroll
  for (int i = 0; i < RED_ITERS; ++i) s += partials[i * 256 + threadIdx.x];
#pragma unroll
  for (int off = 32; off > 0; off >>= 1) s += __shfl_down(s, off);
  if (lane == 0) smem[wave] = s;
  __syncthreads();
  if (threadIdx.x == 0) {
    out[0] = (smem[0] + smem[1] + smem[2] + smem[3]) * (1.0f / (float)N_ROWS);
  }
}

extern "C" void kernel_launch(void* const* d_in, const int* in_sizes, int n_in,
                              void* d_out, int out_size, void* d_ws,
                              size_t ws_size, hipStream_t stream) {
  const float* zi      = (const float*)d_in[0];
  const float* zj      = (const float*)d_in[1];
  const int*   neg_idx = (const int*)d_in[2];
  float* out = (float*)d_out;

  char* w = (char*)d_ws;
  __half* zh      = (__half*)w;                                  // 8 MB
  float*  partials = (float*)(w + (size_t)N_ROWS * D_DIM * sizeof(__half));

  norm_kernel<<<dim3(NORM_BLOCKS), dim3(256), 0, stream>>>(zi, zj, zh);
  loss_kernel<<<dim3(LOSS_BLOCKS), dim3(256), 0, stream>>>(zh, neg_idx,
                                                           partials);
  reduce_kernel<<<dim3(1), dim3(256), 0, stream>>>(partials, out);
}